// Round 18
// baseline (292.562 us; speedup 1.0000x reference)
//
#include <hip/hip_runtime.h>
#include <hip/hip_bf16.h>
#include <stdint.h>

#define NROWS   65536
#define GR      32                // rows per group
#define NGRP    8                 // groups per block
#define RPB     (GR*NGRP)         // 256 rows per block
#define NBLK    (NROWS/RPB)       // 256 blocks = 1 per CU
#define TPB     1024
#define H2N     100
#define KPAD    128
#define N3      1224
#define OUTW    2193
#define TAILN   969
#define NMAIN   77
#define PSTRC   2212              // panel row stride (shorts): 1106 dwords ≡ 18 mod 32

typedef __attribute__((ext_vector_type(8))) short bf16x8;
typedef __attribute__((ext_vector_type(4))) float f32x4;
typedef __attribute__((ext_vector_type(2))) float f32x2;
typedef __attribute__((ext_vector_type(4))) unsigned short u16x4;
typedef __attribute__((ext_vector_type(2))) unsigned int u32x2;

__device__ __forceinline__ float fast_sigmoid(float z){
    return __builtin_amdgcn_rcpf(1.0f + __expf(-z));
}
__device__ __forceinline__ unsigned short f2bf(float v){
    __hip_bfloat16 h = __float2bfloat16(v);
    return *reinterpret_cast<unsigned short*>(&h);
}
__device__ __forceinline__ float bf2f(unsigned short u){
    return __uint_as_float(((unsigned)u) << 16);
}
__device__ __forceinline__ void store16(float* p, f32x4 v){
    __builtin_memcpy(p, &v, 16);
}

// raw barrier: LDS-order only — does NOT drain outstanding global stores
#define BAR() do { asm volatile("s_waitcnt lgkmcnt(0)" ::: "memory");  \
                   __builtin_amdgcn_s_barrier();                        \
                   __builtin_amdgcn_sched_barrier(0); } while(0)

// blocks 0..76: w3f[((t*4+ks)*64+lane)*8+e] = bf16(W3[k][t*16+lm]), b3 folded at k==100.
// blocks 77..80: tail tables pk[p]=(c2<<16)|c1, pw[p]=w[j] (padded to 976).
__global__ void prep_kernel(const float* __restrict__ W3,
                            const float* __restrict__ b3,
                            const float* __restrict__ wgt,
                            const int* __restrict__ idx1,
                            const int* __restrict__ idx2,
                            unsigned short* __restrict__ w3f,
                            unsigned int* __restrict__ pk,
                            float* __restrict__ pw){
    const int blk = blockIdx.x;
    if (blk < NMAIN){
        const int ks   = threadIdx.x >> 6;
        const int lane = threadIdx.x & 63;
        const int lm   = lane & 15, lgf = lane >> 4;
        const int c    = blk * 16 + lm;
        const bool ok  = (c < N3);

        unsigned short vals[8];
        #pragma unroll
        for (int e = 0; e < 8; ++e){
            int k = ks * 32 + lgf * 8 + e;
            float v = 0.0f;
            if (ok){
                if (k < H2N)       v = W3[k * N3 + c];
                else if (k == H2N) v = b3[c];          // bias folded into K
            }
            vals[e] = f2bf(v);
        }
        *reinterpret_cast<bf16x8*>(w3f + ((size_t)(blk * 4 + ks) * 64 + lane) * 8)
            = *reinterpret_cast<bf16x8*>(vals);
    } else {
        const int p = (blk - NMAIN) * 256 + threadIdx.x;
        if (p < 976){
            if (p < TAILN){
                int j = p / 17, k = p - j * 17;
                pk[p] = ((unsigned)(idx2[j] * 17 + k) << 16) | (unsigned)(idx1[j] * 17 + k);
                pw[p] = wgt[j];
            } else { pk[p] = 0; pw[p] = 0.0f; }
        }
    }
}

__global__ __launch_bounds__(TPB, 4)
void snn_kernel(const float* __restrict__ x,
                const float* __restrict__ W1, const float* __restrict__ b1,
                const float* __restrict__ W2, const float* __restrict__ b2,
                const unsigned short* __restrict__ w3f,
                const unsigned int* __restrict__ pk,
                const float* __restrict__ pw,
                float* __restrict__ out)
{
    __shared__ __align__(16) unsigned short panel[GR][PSTRC];   // 141,568 B
    __shared__ __align__(16) unsigned short h2b[GR][KPAD];      //   8,192 B
    __shared__ float w2s[H2N * 10];                             //   4,000 B
    __shared__ float w1s[10], b1s[10];                          //      80 B
    __shared__ __align__(16) unsigned int pks[976];             //   3,904 B
    __shared__ __align__(16) float        pws[976];             //   3,904 B
    // total 161,648 B <= 163,840 -> 1 block/CU

    const int t = threadIdx.x, lane = t & 63, wid = t >> 6;     // 16 waves
    const int lm = lane & 15, lg = lane >> 4;
    const unsigned int rowblk0 = blockIdx.x * RPB;

    #define LOADFRAG(dst, tile) do {                                              \
        const unsigned short* bp_ = w3f + ((size_t)((tile) * 4) * 64 + lane) * 8; \
        _Pragma("unroll")                                                         \
        for (int ks_ = 0; ks_ < 4; ++ks_)                                         \
            dst[ks_] = *reinterpret_cast<const bf16x8*>(bp_ + (size_t)ks_ * 512); \
    } while(0)

    // ---- prologue: stage everything; per-thread group-invariant constants in regs
    for (int i = t; i < H2N * 10; i += TPB) w2s[i] = W2[i];
    if (t < 10){ w1s[t] = W1[t]; b1s[t] = b1[t]; }
    if (t < 976){ pks[t] = pk[t]; pws[t] = pw[t]; }

    const int arow = t >> 5;                 // A-phase row (0..31)
    const int ac0  = (t & 31) << 2;          // A-phase col base (0..124)
    float xreg[NGRP];
    #pragma unroll
    for (int g = 0; g < NGRP; ++g)
        xreg[g] = x[rowblk0 + (g << 5) + arow];
    float b2r[4];
    #pragma unroll
    for (int e = 0; e < 4; ++e)
        b2r[e] = (ac0 + e < H2N) ? b2[ac0 + e] : 0.0f;

    bf16x8 wfr[5][4];                        // W3 frags resident (80 VGPR)
    #pragma unroll
    for (int i = 0; i < 5; ++i){
        const int s = wid + (i << 4);
        if (s < NMAIN) LOADFRAG(wfr[i], s);
    }
    __syncthreads();                         // one full sync (drains prologue loads)

    // ---- 8-group steady state: 2 raw barriers/group, zero global loads
    for (int g = 0; g < NGRP; ++g){
        // ---- A: fused h1+h2 — thread owns (row arow, cols ac0..ac0+3)
        {
            const float xr = xreg[g];
            float h1v[10];
            #pragma unroll
            for (int j = 0; j < 10; ++j)
                h1v[j] = fast_sigmoid(xr * w1s[j] + b1s[j]);
            unsigned short o[4];
            #pragma unroll
            for (int e = 0; e < 4; ++e){
                const int c = ac0 + e;
                if (c < H2N){
                    float z = b2r[e];
                    #pragma unroll
                    for (int j = 0; j < 10; ++j) z += h1v[j] * w2s[j * H2N + c];
                    o[e] = f2bf(fast_sigmoid(z));
                } else o[e] = (c == H2N) ? 0x3F80 : 0;   // 1.0 bias lane / zero pad
            }
            *reinterpret_cast<u16x4*>(&h2b[arow][ac0]) = *reinterpret_cast<u16x4*>(o);
        }
        BAR();                                           // BAR1: h2 ready
        // ---- B: MFMA, 2 row-tiles per slot, register-resident W3 frags -> panel
        {
            bf16x8 hfr[2][4];
            #pragma unroll
            for (int rt = 0; rt < 2; ++rt)
                #pragma unroll
                for (int ks = 0; ks < 4; ++ks)
                    hfr[rt][ks] = *reinterpret_cast<const bf16x8*>(&h2b[rt * 16 + lm][ks * 32 + lg * 8]);
            #pragma unroll
            for (int i = 0; i < 5; ++i){
                const int s = wid + (i << 4);
                if (s < NMAIN){
                    #pragma unroll
                    for (int rt = 0; rt < 2; ++rt){
                        f32x4 a = {0,0,0,0};
                        #pragma unroll
                        for (int ks = 0; ks < 4; ++ks)
                            a = __builtin_amdgcn_mfma_f32_16x16x32_bf16(wfr[i][ks], hfr[rt][ks], a, 0, 0, 0);
                        unsigned short o[4];
                        #pragma unroll
                        for (int r = 0; r < 4; ++r) o[r] = f2bf(fast_sigmoid(a[r]));
                        *reinterpret_cast<u16x4*>(&panel[rt * 16 + lm][(s << 4) + (lg << 2)]) =
                            *reinterpret_cast<u16x4*>(o);
                    }
                }
            }
        }
        BAR();                                           // BAR2: panel main cols ready
        // ---- C: per-wave rows {wid, wid+16} — tail lerp into panel, then dump row
        #pragma unroll
        for (int rr = 0; rr < 2; ++rr){
            const int row = wid + (rr << 4);
            #pragma unroll
            for (int i = 0; i < 8; ++i){
                const int p0 = (lane + (i << 6)) << 1;   // even p, pair (p0, p0+1)
                if (p0 < TAILN){
                    const u32x2 k2 = *reinterpret_cast<const u32x2*>(&pks[p0]);
                    const f32x2 w2v = *reinterpret_cast<const f32x2*>(&pws[p0]);
                    const float a2v = bf2f(panel[row][k2[0] >> 16]);
                    const float a1v = bf2f(panel[row][k2[0] & 0xffffu]);
                    const float b2v = bf2f(panel[row][k2[1] >> 16]);
                    const float b1v = bf2f(panel[row][k2[1] & 0xffffu]);
                    const unsigned short t0 = f2bf(fmaf(w2v[0], a1v - a2v, a2v));
                    const unsigned short t1 = f2bf(fmaf(w2v[1], b1v - b2v, b2v));
                    *reinterpret_cast<unsigned int*>(&panel[row][1232 + p0]) =
                        (unsigned)t0 | ((unsigned)t1 << 16);
                }
            }
            float* orow = out + (size_t)(rowblk0 + (g << 5) + row) * OUTW;
            #pragma unroll
            for (int ch = 0; ch < 9; ++ch){
                const int rc = ch * 256 + (lane << 2);
                if (rc <= 2188){
                    const int vc = rc + (rc >= N3 ? 8 : 0);
                    const u16x4 pv = *reinterpret_cast<const u16x4*>(&panel[row][vc]);
                    f32x4 v;
                    #pragma unroll
                    for (int e = 0; e < 4; ++e) v[e] = bf2f(pv[e]);
                    store16(orow + rc, v);
                } else if (rc == 2192){
                    orow[rc] = bf2f(panel[row][rc + 8]);
                }
            }
        }
        // no barrier: next A writes h2b (safe after BAR2); next B gated by BAR1'
    }
    #undef LOADFRAG
}

extern "C" void kernel_launch(void* const* d_in, const int* in_sizes, int n_in,
                              void* d_out, int out_size, void* d_ws, size_t ws_size,
                              hipStream_t stream)
{
    const float* x   = (const float*)d_in[0];
    const float* W1  = (const float*)d_in[1];
    const float* b1  = (const float*)d_in[2];
    const float* W2  = (const float*)d_in[3];
    const float* b2  = (const float*)d_in[4];
    const float* W3  = (const float*)d_in[5];
    const float* b3  = (const float*)d_in[6];
    const float* wgt = (const float*)d_in[7];
    const int*   i1  = (const int*)d_in[8];
    const int*   i2  = (const int*)d_in[9];
    float* out = (float*)d_out;

    unsigned char* ws = (unsigned char*)d_ws;
    unsigned short* w3f = (unsigned short*)ws;                 // 315,392 B
    unsigned int*   pk  = (unsigned int*)(ws + 315392);        // 3,904 B
    float*          pw  = (float*)(ws + 315392 + 3904);        // 3,904 B

    prep_kernel<<<NMAIN + 4, 256, 0, stream>>>(W3, b3, wgt, i1, i2, w3f, pk, pw);
    snn_kernel<<<NBLK, TPB, 0, stream>>>(x, W1, b1, W2, b2, w3f, pk, pw, out);
}

// Round 19
// 136.542 us; speedup vs baseline: 2.1427x; 2.1427x over previous
//
#include <hip/hip_runtime.h>
#include <hip/hip_bf16.h>
#include <stdint.h>

#define NROWS   65536
#define GR      32                // rows per group
#define NGRP    8                 // groups per block
#define RPB     (GR*NGRP)         // 256 rows per block
#define NBLK    (NROWS/RPB)       // 256 blocks = 1 per CU
#define TPB     1024
#define H2N     100
#define KPAD    128
#define N3      1224
#define OUTW    2193
#define TAILN   969
#define NMAIN   77
#define PSTRC   2212              // panel row stride (shorts)

typedef __attribute__((ext_vector_type(8))) short bf16x8;
typedef __attribute__((ext_vector_type(4))) float f32x4;
typedef __attribute__((ext_vector_type(2))) float f32x2;
typedef __attribute__((ext_vector_type(4))) unsigned short u16x4;
typedef __attribute__((ext_vector_type(2))) unsigned int u32x2;

__device__ __forceinline__ float fast_sigmoid(float z){
    return __builtin_amdgcn_rcpf(1.0f + __expf(-z));
}
__device__ __forceinline__ unsigned short f2bf(float v){
    __hip_bfloat16 h = __float2bfloat16(v);
    return *reinterpret_cast<unsigned short*>(&h);
}
__device__ __forceinline__ float bf2f(unsigned short u){
    return __uint_as_float(((unsigned)u) << 16);
}
__device__ __forceinline__ void store16(float* p, f32x4 v){
    __builtin_memcpy(p, &v, 16);
}

// raw barrier: LDS-order only — does NOT drain outstanding global stores
#define BAR() do { asm volatile("s_waitcnt lgkmcnt(0)" ::: "memory");  \
                   __builtin_amdgcn_s_barrier();                        \
                   __builtin_amdgcn_sched_barrier(0); } while(0)

// blocks 0..76: w3f[((t*4+ks)*64+lane)*8+e] = bf16(W3[k][t*16+lm]), b3 folded at k==100.
// blocks 77..80: tail tables pk[p]=(c2<<16)|c1, pw[p]=w[j] (padded to 976).
__global__ void prep_kernel(const float* __restrict__ W3,
                            const float* __restrict__ b3,
                            const float* __restrict__ wgt,
                            const int* __restrict__ idx1,
                            const int* __restrict__ idx2,
                            unsigned short* __restrict__ w3f,
                            unsigned int* __restrict__ pk,
                            float* __restrict__ pw){
    const int blk = blockIdx.x;
    if (blk < NMAIN){
        const int ks   = threadIdx.x >> 6;
        const int lane = threadIdx.x & 63;
        const int lm   = lane & 15, lgf = lane >> 4;
        const int c    = blk * 16 + lm;
        const bool ok  = (c < N3);

        unsigned short vals[8];
        #pragma unroll
        for (int e = 0; e < 8; ++e){
            int k = ks * 32 + lgf * 8 + e;
            float v = 0.0f;
            if (ok){
                if (k < H2N)       v = W3[k * N3 + c];
                else if (k == H2N) v = b3[c];          // bias folded into K
            }
            vals[e] = f2bf(v);
        }
        *reinterpret_cast<bf16x8*>(w3f + ((size_t)(blk * 4 + ks) * 64 + lane) * 8)
            = *reinterpret_cast<bf16x8*>(vals);
    } else {
        const int p = (blk - NMAIN) * 256 + threadIdx.x;
        if (p < 976){
            if (p < TAILN){
                int j = p / 17, k = p - j * 17;
                pk[p] = ((unsigned)(idx2[j] * 17 + k) << 16) | (unsigned)(idx1[j] * 17 + k);
                pw[p] = wgt[j];
            } else { pk[p] = 0; pw[p] = 0.0f; }
        }
    }
}

__global__ __launch_bounds__(TPB, 4)
void snn_kernel(const float* __restrict__ x,
                const float* __restrict__ W1, const float* __restrict__ b1,
                const float* __restrict__ W2, const float* __restrict__ b2,
                const unsigned short* __restrict__ w3f,
                const unsigned int* __restrict__ pk,
                const float* __restrict__ pw,
                float* __restrict__ out)
{
    __shared__ __align__(16) unsigned short panel[GR][PSTRC];   // 141,568 B
    __shared__ __align__(16) unsigned short h2b[GR][KPAD];      //   8,192 B
    __shared__ float w2s[H2N * 10];                             //   4,000 B
    __shared__ float b2s[H2N];                                  //     400 B
    __shared__ float xs[RPB];                                   //   1,024 B
    __shared__ float w1s[10], b1s[10];                          //      80 B
    __shared__ __align__(16) unsigned int pks[976];             //   3,904 B
    __shared__ __align__(16) float        pws[976];             //   3,904 B
    // total 163,072 B <= 163,840 -> 1 block/CU

    const int t = threadIdx.x, lane = t & 63, wid = t >> 6;     // 16 waves
    const int lm = lane & 15, lg = lane >> 4;
    const unsigned int rowblk0 = blockIdx.x * RPB;

    #define LOADFRAG(dst, tile) do {                                              \
        const unsigned short* bp_ = w3f + ((size_t)((tile) * 4) * 64 + lane) * 8; \
        _Pragma("unroll")                                                         \
        for (int ks_ = 0; ks_ < 4; ++ks_)                                         \
            dst[ks_] = *reinterpret_cast<const bf16x8*>(bp_ + (size_t)ks_ * 512); \
    } while(0)

    // ---- prologue: stage everything (only global loads in this kernel)
    for (int i = t; i < H2N * 10; i += TPB) w2s[i] = W2[i];
    if (t < H2N) b2s[t] = b2[t];
    if (t < 10){ w1s[t] = W1[t]; b1s[t] = b1[t]; }
    if (t < RPB) xs[t] = x[rowblk0 + t];
    if (t < 976){ pks[t] = pk[t]; pws[t] = pw[t]; }

    bf16x8 wfr[5][4];                        // W3 frags resident (80 VGPR)
    #pragma unroll
    for (int i = 0; i < 5; ++i){
        const int s = wid + (i << 4);
        if (s < NMAIN) LOADFRAG(wfr[i], s);
    }
    __syncthreads();                         // one full sync (drains prologue loads)

    const int arow = t >> 5;                 // A-phase row (0..31)
    const int ac0  = (t & 31) << 2;          // A-phase col base (0..124)

    // ---- 8-group steady state: 2 raw barriers/group, zero global loads
    for (int g = 0; g < NGRP; ++g){
        // ---- A: fused h1+h2 — thread owns (row arow, cols ac0..ac0+3)
        {
            const float xr = xs[(g << 5) + arow];
            float h1v[10];
            #pragma unroll
            for (int j = 0; j < 10; ++j)
                h1v[j] = fast_sigmoid(xr * w1s[j] + b1s[j]);
            unsigned short o[4];
            #pragma unroll
            for (int e = 0; e < 4; ++e){
                const int c = ac0 + e;
                if (c < H2N){
                    float z = b2s[c];
                    #pragma unroll
                    for (int j = 0; j < 10; ++j) z += h1v[j] * w2s[j * H2N + c];
                    o[e] = f2bf(fast_sigmoid(z));
                } else o[e] = (c == H2N) ? 0x3F80 : 0;   // 1.0 bias lane / zero pad
            }
            *reinterpret_cast<u16x4*>(&h2b[arow][ac0]) = *reinterpret_cast<u16x4*>(o);
        }
        BAR();                                           // BAR1: h2 ready
        // ---- B: MFMA — row-tiles OUTER (hfr only 16 VGPR live), slots inner
        #pragma unroll
        for (int rt = 0; rt < 2; ++rt){
            bf16x8 hfr[4];
            #pragma unroll
            for (int ks = 0; ks < 4; ++ks)
                hfr[ks] = *reinterpret_cast<const bf16x8*>(&h2b[rt * 16 + lm][ks * 32 + lg * 8]);
            #pragma unroll
            for (int i = 0; i < 5; ++i){
                const int s = wid + (i << 4);
                if (s < NMAIN){
                    f32x4 a = {0,0,0,0};
                    #pragma unroll
                    for (int ks = 0; ks < 4; ++ks)
                        a = __builtin_amdgcn_mfma_f32_16x16x32_bf16(wfr[i][ks], hfr[ks], a, 0, 0, 0);
                    unsigned short o[4];
                    #pragma unroll
                    for (int r = 0; r < 4; ++r) o[r] = f2bf(fast_sigmoid(a[r]));
                    *reinterpret_cast<u16x4*>(&panel[rt * 16 + lm][(s << 4) + (lg << 2)]) =
                        *reinterpret_cast<u16x4*>(o);
                }
            }
        }
        BAR();                                           // BAR2: panel main cols ready
        // ---- C: per-wave rows {wid, wid+16} — tail lerp into panel, then dump row
        #pragma unroll
        for (int rr = 0; rr < 2; ++rr){
            const int row = wid + (rr << 4);
            #pragma unroll
            for (int i = 0; i < 8; ++i){
                const int p0 = (lane + (i << 6)) << 1;   // even p, pair (p0, p0+1)
                if (p0 < TAILN){
                    const u32x2 k2 = *reinterpret_cast<const u32x2*>(&pks[p0]);
                    const f32x2 w2v = *reinterpret_cast<const f32x2*>(&pws[p0]);
                    const float a2v = bf2f(panel[row][k2[0] >> 16]);
                    const float a1v = bf2f(panel[row][k2[0] & 0xffffu]);
                    const float b2v = bf2f(panel[row][k2[1] >> 16]);
                    const float b1v = bf2f(panel[row][k2[1] & 0xffffu]);
                    const unsigned short t0 = f2bf(fmaf(w2v[0], a1v - a2v, a2v));
                    const unsigned short t1 = f2bf(fmaf(w2v[1], b1v - b2v, b2v));
                    *reinterpret_cast<unsigned int*>(&panel[row][1232 + p0]) =
                        (unsigned)t0 | ((unsigned)t1 << 16);
                }
            }
            float* orow = out + (size_t)(rowblk0 + (g << 5) + row) * OUTW;
            #pragma unroll
            for (int ch = 0; ch < 9; ++ch){
                const int rc = ch * 256 + (lane << 2);
                if (rc <= 2188){
                    const int vc = rc + (rc >= N3 ? 8 : 0);
                    const u16x4 pv = *reinterpret_cast<const u16x4*>(&panel[row][vc]);
                    f32x4 v;
                    #pragma unroll
                    for (int e = 0; e < 4; ++e) v[e] = bf2f(pv[e]);
                    store16(orow + rc, v);
                } else if (rc == 2192){
                    orow[rc] = bf2f(panel[row][rc + 8]);
                }
            }
        }
        // no barrier: next A writes h2b (safe after BAR2); next B gated by BAR1'
    }
    #undef LOADFRAG
}

extern "C" void kernel_launch(void* const* d_in, const int* in_sizes, int n_in,
                              void* d_out, int out_size, void* d_ws, size_t ws_size,
                              hipStream_t stream)
{
    const float* x   = (const float*)d_in[0];
    const float* W1  = (const float*)d_in[1];
    const float* b1  = (const float*)d_in[2];
    const float* W2  = (const float*)d_in[3];
    const float* b2  = (const float*)d_in[4];
    const float* W3  = (const float*)d_in[5];
    const float* b3  = (const float*)d_in[6];
    const float* wgt = (const float*)d_in[7];
    const int*   i1  = (const int*)d_in[8];
    const int*   i2  = (const int*)d_in[9];
    float* out = (float*)d_out;

    unsigned char* ws = (unsigned char*)d_ws;
    unsigned short* w3f = (unsigned short*)ws;                 // 315,392 B
    unsigned int*   pk  = (unsigned int*)(ws + 315392);        // 3,904 B
    float*          pw  = (float*)(ws + 315392 + 3904);        // 3,904 B

    prep_kernel<<<NMAIN + 4, 256, 0, stream>>>(W3, b3, wgt, i1, i2, w3f, pk, pw);
    snn_kernel<<<NBLK, TPB, 0, stream>>>(x, W1, b1, W2, b2, w3f, pk, pw, out);
}